// Round 17
// baseline (142.975 us; speedup 1.0000x reference)
//
#include <hip/hip_runtime.h>

typedef _Float16 h16x8 __attribute__((ext_vector_type(8)));
typedef float f32x4 __attribute__((ext_vector_type(4)));

#define MFMA16F(a, b, c) __builtin_amdgcn_mfma_f32_16x16x32_f16((a), (b), (c), 0, 0, 0)

#define GLOAD16(gp, lp)                                                        \
  __builtin_amdgcn_global_load_lds(                                            \
      (const __attribute__((address_space(1))) unsigned int*)(gp),             \
      (__attribute__((address_space(3))) unsigned int*)(lp), 16, 0, 0)

#define FENCE() __builtin_amdgcn_sched_barrier(0)

// Geometry: x (8, 256, 16384) fp32; mem (200, 256) fp32; out (8, 256, 16384) fp32.
// Slots padded 200 -> 256 with zero rows.
// Score: fp16 2-pass split (R12-proven). PV: R13 orientation (P = A-operand,
// pure-register from score acc; MB = B-frag-tiled mem table, linear LDS reads;
// token-contiguous f32x4 stores). ALL barriers are full-drain __syncthreads.
// CRITICAL: acc MUST be [14] -- the PV repack reads acc[13] for kk=6,j>=4
// (padding slots 208..223, must be exact 0). R15/R16 failed on acc[13] OOB.

// ---------------- prep: mem -> fp16 M16 (row-major) + MB (B-frag-tiled) ----------------
__global__ __launch_bounds__(256) void prep_mem(const float* __restrict__ mem,
                                                unsigned short* __restrict__ M16,
                                                unsigned short* __restrict__ MB) {
  const int s = blockIdx.x;   // slot (padded 0..255)
  const int c = threadIdx.x;  // channel
  const float v = (s < 200) ? mem[s * 256 + c] : 0.0f;
  const _Float16 hv = (_Float16)v;
  const unsigned short hb = __builtin_bit_cast(unsigned short, hv);
  M16[s * 256 + c] = hb;
  if (s < 224) {
    // invert s(kk,h,j): s = 32kk + 16*(j>>2) + 4h + (j&3)
    const int kk = s >> 5;
    const int th = (s >> 4) & 1;   // j>>2
    const int hh = (s >> 2) & 3;
    const int rr = s & 3;          // j&3
    const int j = th * 4 + rr;
    MB[kk * 8192 + (c >> 4) * 512 + hh * 128 + (c & 15) * 8 + j] = hb;
  }
}

// ---------------- fused kernel ----------------
// Block = 16 waves x 16 tokens = 256 tokens/tile, 1024 threads. Grid = 256,
// PERSISTENT over 2 contiguous tiles (512 tokens/block, same batch).
// Per tile: [stage M16 | score barrier-free | bar | stage MB (+ next tile's
// x prefetch) | softmax | bar | PV barrier-free + stores]. Tile boundary is a
// full __syncthreads; tile-1's score starts with x slices 0,1 already in regs.
__global__ __launch_bounds__(1024, 4) void fused_mem_attn(
    const float* __restrict__ x, const unsigned short* __restrict__ M16,
    const unsigned short* __restrict__ MB, float* __restrict__ out) {
  __shared__ alignas(128) char lds[131072];

  const int tid = threadIdx.x;   // 0..1023
  const int wave = tid >> 6;     // 0..15
  const int lane = tid & 63;
  const int t16 = lane & 15;
  const int h = lane >> 4;

  // Score-table staging swizzle (proven pair): thread owns physical 16B-block
  // tid of each 16KB slice; fetches logical Lb = tid ^ ((tid>>3)&7).
  const int Lb = tid ^ ((tid >> 3) & 7);
  const int srcOff = (Lb >> 2) * 512 + (Lb & 3) * 16;  // byte in [256 rows][64B]
  // Reader-side swizzled 16B-block offset within a 1KB (16-row) tile.
  const int q16 = ((((t16 << 2) + h) ^ (t16 >> 1)) << 4);

  // Block's 512 tokens: bid*512 .. bid*512+511 (512 | 16384 -> one batch).
  const long base0 = (long)blockIdx.x * 512;
  const int b = (int)(base0 >> 14);
  const int bn0 = (int)(base0 & 16383);
  const float* xA = x + ((long)b << 22) + bn0 + (wave * 16 + t16);
  const float* xBp = xA + 256;
  float* oA = out + ((long)b << 22) + bn0 + (wave * 16 + 4 * h) + ((long)t16 << 14);
  float* oB = oA + 256;

  const char* M16B = (const char*)M16;
  const char* MBB = (const char*)MB;

  float xr[3][8];

#define STAGE_M16()                                                            \
  _Pragma("unroll") for (int ks = 0; ks < 8; ++ks)                             \
      GLOAD16(M16B + srcOff + ks * 64, lds + ks * 16384 + tid * 16);

#define STAGE_MB()                                                             \
  _Pragma("unroll") for (int k = 0; k < 7; ++k)                                \
      GLOAD16(MBB + k * 16384 + tid * 16, lds + k * 16384 + tid * 16);

#define XLOAD(XP, ks)                                                          \
  _Pragma("unroll") for (int j = 0; j < 8; ++j) {                              \
    xr[(ks) % 3][j] = (XP)[(long)((ks) * 32 + h * 8 + j) << 14];               \
  }

#define COMPUTE(XP, ks)                                                        \
  {                                                                            \
    if ((ks) < 6) XLOAD(XP, (ks) + 2);                                         \
    h16x8 xh, xl;                                                              \
    _Pragma("unroll") for (int j = 0; j < 8; ++j) {                            \
      const float f = xr[(ks) % 3][j];                                         \
      const _Float16 hi_ = (_Float16)f;                                        \
      xh[j] = hi_;                                                             \
      xl[j] = (_Float16)(f - (float)hi_);                                      \
    }                                                                          \
    const char* sb = lds + (ks) * 16384;                                       \
    __builtin_amdgcn_s_setprio(1);                                             \
    _Pragma("unroll") for (int tt = 0; tt < 13; ++tt) {                        \
      const h16x8 ah = *(const h16x8*)(sb + tt * 1024 + q16);                  \
      acc[tt] = MFMA16F(ah, xh, acc[tt]);                                      \
      acc[tt] = MFMA16F(ah, xl, acc[tt]);                                      \
    }                                                                          \
    __builtin_amdgcn_s_setprio(0);                                             \
    FENCE();                                                                   \
  }

#define SOFTMAX_REPACK()                                                       \
  {                                                                            \
    float m = -3.0e38f;                                                        \
    _Pragma("unroll") for (int tt = 0; tt < 12; ++tt)                          \
        _Pragma("unroll") for (int r = 0; r < 4; ++r)                          \
            m = fmaxf(m, acc[tt][r]);                                          \
    _Pragma("unroll") for (int r = 0; r < 4; ++r)                              \
        if (192 + h * 4 + r < 200) m = fmaxf(m, acc[12][r]);                   \
    m = fmaxf(m, __shfl_xor(m, 16, 64));                                       \
    m = fmaxf(m, __shfl_xor(m, 32, 64));                                       \
    float s = 0.f;                                                             \
    _Pragma("unroll") for (int tt = 0; tt < 12; ++tt)                          \
        _Pragma("unroll") for (int r = 0; r < 4; ++r) {                        \
      const float p = __expf(acc[tt][r] - m);                                  \
      acc[tt][r] = p;                                                          \
      s += p;                                                                  \
    }                                                                          \
    _Pragma("unroll") for (int r = 0; r < 4; ++r) {                            \
      const bool ok = (192 + h * 4 + r) < 200;                                 \
      const float p = ok ? __expf(acc[12][r] - m) : 0.f;                       \
      acc[12][r] = p;                                                          \
      s += p;                                                                  \
    }                                                                          \
    s += __shfl_xor(s, 16, 64);                                                \
    s += __shfl_xor(s, 32, 64);                                                \
    const float inv = 1.f / s;                                                 \
    _Pragma("unroll") for (int kk = 0; kk < 7; ++kk)                           \
        _Pragma("unroll") for (int j = 0; j < 8; ++j)                          \
            pa[kk][j] = (_Float16)(inv * acc[2 * kk + (j >> 2)][j & 3]);       \
  }

#define PV_PHASE(OB)                                                           \
  _Pragma("unroll") for (int ct = 0; ct < 16; ++ct) {                          \
    f32x4 a2 = {0.f, 0.f, 0.f, 0.f};                                           \
    __builtin_amdgcn_s_setprio(1);                                             \
    _Pragma("unroll") for (int kk = 0; kk < 7; ++kk) {                         \
      const h16x8 bt =                                                         \
          *(const h16x8*)(lds + kk * 16384 + ct * 1024 + lane * 16);           \
      a2 = MFMA16F(pa[kk], bt, a2);                                            \
    }                                                                          \
    __builtin_amdgcn_s_setprio(0);                                             \
    *(f32x4*)((OB) + ((long)ct << 18)) = a2;                                   \
  }

  // ================= tile 0 =================
  {
    XLOAD(xA, 0);
    XLOAD(xA, 1);
    STAGE_M16();
    __syncthreads();  // B1: M16 resident (full drain)

    f32x4 acc[14] = {};  // acc[13] stays EXACTLY 0 (padding slots 208..223,
                         // read by the repack for kk=6,j>=4 -- must be [14]!)
    h16x8 pa[7];

    COMPUTE(xA, 0) COMPUTE(xA, 1) COMPUTE(xA, 2) COMPUTE(xA, 3)
    COMPUTE(xA, 4) COMPUTE(xA, 5) COMPUTE(xA, 6) COMPUTE(xA, 7)

    __syncthreads();  // B2: all waves' M16 reads retired
    STAGE_MB();
    XLOAD(xBp, 0);    // tile-1 x prefetch: hides under softmax + PV
    XLOAD(xBp, 1);

    SOFTMAX_REPACK();

    __syncthreads();  // B3: publishes MB (drains MB stage + prefetch)

    PV_PHASE(oA);
  }

  __syncthreads();  // B4 (boundary, full drain): MB reads retired everywhere

  // ================= tile 1 =================
  {
    STAGE_M16();
    __syncthreads();  // B5: M16 resident again

    f32x4 acc[14] = {};  // same: [14], acc[13] == 0
    h16x8 pa[7];

    COMPUTE(xBp, 0) COMPUTE(xBp, 1) COMPUTE(xBp, 2) COMPUTE(xBp, 3)
    COMPUTE(xBp, 4) COMPUTE(xBp, 5) COMPUTE(xBp, 6) COMPUTE(xBp, 7)

    __syncthreads();  // B6: M16 reads retired
    STAGE_MB();

    SOFTMAX_REPACK();

    __syncthreads();  // B7: publishes MB

    PV_PHASE(oB);
  }
#undef STAGE_M16
#undef STAGE_MB
#undef XLOAD
#undef COMPUTE
#undef SOFTMAX_REPACK
#undef PV_PHASE
}

extern "C" void kernel_launch(void* const* d_in, const int* in_sizes, int n_in,
                              void* d_out, int out_size, void* d_ws, size_t ws_size,
                              hipStream_t stream) {
  const float* x = (const float*)d_in[0];
  const float* mem = (const float*)d_in[1];
  float* out = (float*)d_out;

  unsigned short* M16 = (unsigned short*)d_ws;   // [256][256] fp16 row-major
  unsigned short* MB = M16 + 256 * 256;          // [7][16][4][16][8] fp16 B-frag tiling

  prep_mem<<<dim3(256), dim3(256), 0, stream>>>(mem, M16, MB);
  fused_mem_attn<<<dim3(256), dim3(1024), 0, stream>>>(x, M16, MB, out);
}

// Round 18
// 68.345 us; speedup vs baseline: 2.0920x; 2.0920x over previous
//
#include <hip/hip_runtime.h>

typedef _Float16 h16x8 __attribute__((ext_vector_type(8)));
typedef float f32x4 __attribute__((ext_vector_type(4)));

#define MFMA16F(a, b, c) __builtin_amdgcn_mfma_f32_16x16x32_f16((a), (b), (c), 0, 0, 0)

#define GLOAD16(gp, lp)                                                        \
  __builtin_amdgcn_global_load_lds(                                            \
      (const __attribute__((address_space(1))) unsigned int*)(gp),             \
      (__attribute__((address_space(3))) unsigned int*)(lp), 16, 0, 0)

#define FENCE() __builtin_amdgcn_sched_barrier(0)

// Geometry: x (8, 256, 16384) fp32; mem (200, 256) fp32; out (8, 256, 16384) fp32.
// Slots padded 200 -> 256 with zero rows.
//
// Score: fp16 2-pass split (m16*xh + m16*xl, fp32 accum) -- R12-proven.
// PV: reoriented as D[tok][c] = P*M so the A-operand is a PURE-REGISTER view of
// the score accumulators: with k-order s(32kk+8h+j) = 32kk+16(j>>2)+4h+(j&3),
// pa[kk][j] = inv*acc[2kk+(j>>2)][j&3] (same lane, no shuffle). B = mem in a
// B-fragment-linear pre-tiled table MB (conflict-free linear LDS reads, no
// swizzle), and the output C-layout gives 16B dwordx4 token-contiguous stores.

// ---------------- prep: mem -> fp16 M16 (row-major) + MB (B-frag-tiled) ----------------
__global__ __launch_bounds__(256) void prep_mem(const float* __restrict__ mem,
                                                unsigned short* __restrict__ M16,
                                                unsigned short* __restrict__ MB) {
  const int s = blockIdx.x;   // slot (padded 0..255)
  const int c = threadIdx.x;  // channel
  const float v = (s < 200) ? mem[s * 256 + c] : 0.0f;
  const _Float16 hv = (_Float16)v;
  const unsigned short hb = __builtin_bit_cast(unsigned short, hv);
  M16[s * 256 + c] = hb;
  if (s < 224) {
    // invert s(kk,h,j): s = 32kk + 16*(j>>2) + 4h + (j&3)
    const int kk = s >> 5;
    const int th = (s >> 4) & 1;   // j>>2
    const int hh = (s >> 2) & 3;
    const int rr = s & 3;          // j&3
    const int j = th * 4 + rr;
    // element idx = kk*8192 + (c>>4)*512 + hh*128 + (c&15)*8 + j
    MB[kk * 8192 + (c >> 4) * 512 + hh * 128 + (c & 15) * 8 + j] = hb;
  }
}

// ---------------- fused kernel ----------------
// Block = 16 waves x 16 tokens = 256 tokens, 1024 threads. Grid = 512.
// LDS 128KB = ALL 8 M16 slices resident; score phase BARRIER-FREE (only the
// bounded 2-deep x prefetch in flight). 3 runtime barriers total. MB (7x16KB)
// staged over dead M16 slices, fill hidden under softmax/repack.
__global__ __launch_bounds__(1024, 4) void fused_mem_attn(
    const float* __restrict__ x, const unsigned short* __restrict__ M16,
    const unsigned short* __restrict__ MB, float* __restrict__ out) {
  __shared__ alignas(128) char lds[131072];

  const int tid = threadIdx.x;   // 0..1023
  const int wave = tid >> 6;     // 0..15
  const int lane = tid & 63;
  const int t16 = lane & 15;
  const int h = lane >> 4;

  // Score-table staging swizzle (proven pair): thread owns physical 16B-block
  // tid of each 16KB slice; fetches logical Lb = tid ^ ((tid>>3)&7).
  const int Lb = tid ^ ((tid >> 3) & 7);
  const int srcOff = (Lb >> 2) * 512 + (Lb & 3) * 16;  // byte in [256 rows][64B]
  // Reader-side swizzled 16B-block offset within a 1KB (16-row) tile.
  const int q16 = ((((t16 << 2) + h) ^ (t16 >> 1)) << 4);

  const long gtok0 = (long)blockIdx.x * 256;
  const int b = (int)(gtok0 >> 14);
  const int bn0 = (int)(gtok0 & 16383);
  const float* xb = x + ((long)b << 22) + bn0 + (wave * 16 + t16);
  // PV store base: token = wave*16 + 4h + r (r in the f32x4), channel = ct*16+t16
  float* outT = out + ((long)b << 22) + bn0 + (wave * 16 + 4 * h) + ((long)t16 << 14);

  const char* M16B = (const char*)M16;
  const char* MBB = (const char*)MB;

#define XLOAD(ks)                                                              \
  _Pragma("unroll") for (int j = 0; j < 8; ++j) {                              \
    xr[(ks) % 3][j] = xb[(long)((ks) * 32 + h * 8 + j) << 14];                 \
  }

  float xr[3][8];
  f32x4 acc[14] = {};  // acc[13] stays exactly 0 (padding slots 208..223)

#define COMPUTE(ks)                                                            \
  {                                                                            \
    if ((ks) < 6) XLOAD((ks) + 2);                                             \
    h16x8 xh, xl;                                                              \
    _Pragma("unroll") for (int j = 0; j < 8; ++j) {                            \
      const float f = xr[(ks) % 3][j];                                         \
      const _Float16 hi_ = (_Float16)f;                                        \
      xh[j] = hi_;                                                             \
      xl[j] = (_Float16)(f - (float)hi_);                                      \
    }                                                                          \
    const char* sb = lds + (ks) * 16384;                                       \
    __builtin_amdgcn_s_setprio(1);                                             \
    _Pragma("unroll") for (int tt = 0; tt < 13; ++tt) {                        \
      const h16x8 ah = *(const h16x8*)(sb + tt * 1024 + q16);                  \
      acc[tt] = MFMA16F(ah, xh, acc[tt]);                                      \
      acc[tt] = MFMA16F(ah, xl, acc[tt]);                                      \
    }                                                                          \
    __builtin_amdgcn_s_setprio(0);                                             \
    FENCE();                                                                   \
  }

  // ---- prologue: 2-deep x prefetch + stage ALL 8 M16 slices; barrier #1 ----
  XLOAD(0);
  XLOAD(1);
#pragma unroll
  for (int ks = 0; ks < 8; ++ks)
    GLOAD16(M16B + srcOff + ks * 64, lds + ks * 16384 + tid * 16);
  __syncthreads();

  // ---- score phase: BARRIER-FREE, zero global fragment loads ----
  COMPUTE(0) COMPUTE(1) COMPUTE(2) COMPUTE(3)
  COMPUTE(4) COMPUTE(5) COMPUTE(6) COMPUTE(7)

  __syncthreads();  // barrier #2: all waves done reading M16 LDS

  // ---- stage ALL of MB (7 x 16KB, LINEAR dest/src: no swizzle needed) over
  //      the dead score slices; fill hides under softmax + repack ----
#pragma unroll
  for (int k = 0; k < 7; ++k)
    GLOAD16(MBB + k * 16384 + tid * 16, lds + k * 16384 + tid * 16);

  // ---- softmax over slots (token column = lane&15; slot row = 4h+r) ----
  float m = -3.0e38f;
#pragma unroll
  for (int tt = 0; tt < 12; ++tt)
#pragma unroll
    for (int r = 0; r < 4; ++r) m = fmaxf(m, acc[tt][r]);
#pragma unroll
  for (int r = 0; r < 4; ++r)
    if (192 + h * 4 + r < 200) m = fmaxf(m, acc[12][r]);
  m = fmaxf(m, __shfl_xor(m, 16, 64));
  m = fmaxf(m, __shfl_xor(m, 32, 64));
  float s = 0.f;
#pragma unroll
  for (int tt = 0; tt < 12; ++tt)
#pragma unroll
    for (int r = 0; r < 4; ++r) {
      const float p = __expf(acc[tt][r] - m);
      acc[tt][r] = p;
      s += p;
    }
#pragma unroll
  for (int r = 0; r < 4; ++r) {
    const bool ok = (192 + h * 4 + r) < 200;
    const float p = ok ? __expf(acc[12][r] - m) : 0.f;
    acc[12][r] = p;
    s += p;
  }
  s += __shfl_xor(s, 16, 64);
  s += __shfl_xor(s, 32, 64);
  const float inv = 1.f / s;

  // ---- repack P into PV A-fragments, inv folded in (pure register):
  //      pa[kk][j] = inv * acc[2kk + (j>>2)][j&3]  (same lane, same h) ----
  h16x8 pa[7];
#pragma unroll
  for (int kk = 0; kk < 7; ++kk)
#pragma unroll
    for (int j = 0; j < 8; ++j)
      pa[kk][j] = (_Float16)(inv * acc[2 * kk + (j >> 2)][j & 3]);

  __syncthreads();  // barrier #3: MB resident

  // ---- PV: D[tok][c] = P*M. B-fragments linear from LDS (conflict-free);
  //      output f32x4 = 4 consecutive tokens -> ONE 16B dwordx4 store ----
#pragma unroll
  for (int ct = 0; ct < 16; ++ct) {
    f32x4 a2 = {0.f, 0.f, 0.f, 0.f};
    __builtin_amdgcn_s_setprio(1);
#pragma unroll
    for (int kk = 0; kk < 7; ++kk) {
      const h16x8 bt = *(const h16x8*)(lds + kk * 16384 + ct * 1024 + lane * 16);
      a2 = MFMA16F(pa[kk], bt, a2);
    }
    __builtin_amdgcn_s_setprio(0);
    *(f32x4*)(outT + ((long)ct << 18)) = a2;
  }
#undef XLOAD
#undef COMPUTE
}

extern "C" void kernel_launch(void* const* d_in, const int* in_sizes, int n_in,
                              void* d_out, int out_size, void* d_ws, size_t ws_size,
                              hipStream_t stream) {
  const float* x = (const float*)d_in[0];
  const float* mem = (const float*)d_in[1];
  float* out = (float*)d_out;

  unsigned short* M16 = (unsigned short*)d_ws;   // [256][256] fp16 row-major
  unsigned short* MB = M16 + 256 * 256;          // [7][16][4][16][8] fp16 B-frag tiling

  prep_mem<<<dim3(256), dim3(256), 0, stream>>>(mem, M16, MB);
  fused_mem_attn<<<dim3(512), dim3(1024), 0, stream>>>(x, M16, MB, out);
}

// Round 19
// 62.122 us; speedup vs baseline: 2.3015x; 1.1002x over previous
//
#include <hip/hip_runtime.h>

typedef _Float16 h16x8 __attribute__((ext_vector_type(8)));
typedef float f32x4 __attribute__((ext_vector_type(4)));

#define MFMA16F(a, b, c) __builtin_amdgcn_mfma_f32_16x16x32_f16((a), (b), (c), 0, 0, 0)

#define GLOAD16(gp, lp)                                                        \
  __builtin_amdgcn_global_load_lds(                                            \
      (const __attribute__((address_space(1))) unsigned int*)(gp),             \
      (__attribute__((address_space(3))) unsigned int*)(lp), 16, 0, 0)

#define FENCE() __builtin_amdgcn_sched_barrier(0)

// Geometry: x (8, 256, 16384) fp32; mem (200, 256) fp32; out (8, 256, 16384) fp32.
// Slots padded 200 -> 256 with zero rows.
//
// Score: SINGLE-PASS fp16 (m16 * fp16(x), fp32 accum). vs the 2-pass split
// this adds x-rounding error of the same magnitude as the (already present,
// uncorrected) mem-rounding error: logit err ~2.4e-3 -> ~3.4e-3, est. output
// absmax 0.04-0.06 vs threshold 0.0875. Halves score MFMAs + drops xl VALU.
// PV: R13 orientation (P = A-operand, pure-register from score acc; MB =
// B-frag-tiled mem table, linear LDS reads; token-contiguous f32x4 stores).
// CRITICAL: acc MUST be [14] -- repack reads acc[13] for kk=6,j>=4 (zero pad).

// ---------------- prep: mem -> fp16 M16 (row-major) + MB (B-frag-tiled) ----------------
__global__ __launch_bounds__(256) void prep_mem(const float* __restrict__ mem,
                                                unsigned short* __restrict__ M16,
                                                unsigned short* __restrict__ MB) {
  const int s = blockIdx.x;   // slot (padded 0..255)
  const int c = threadIdx.x;  // channel
  const float v = (s < 200) ? mem[s * 256 + c] : 0.0f;
  const _Float16 hv = (_Float16)v;
  const unsigned short hb = __builtin_bit_cast(unsigned short, hv);
  M16[s * 256 + c] = hb;
  if (s < 224) {
    // invert s(kk,h,j): s = 32kk + 16*(j>>2) + 4h + (j&3)
    const int kk = s >> 5;
    const int th = (s >> 4) & 1;   // j>>2
    const int hh = (s >> 2) & 3;
    const int rr = s & 3;          // j&3
    const int j = th * 4 + rr;
    MB[kk * 8192 + (c >> 4) * 512 + hh * 128 + (c & 15) * 8 + j] = hb;
  }
}

// ---------------- fused kernel ----------------
// Block = 16 waves x 16 tokens = 256 tokens, 1024 threads. Grid = 512.
// LDS 128KB = ALL 8 M16 slices resident; score phase BARRIER-FREE (only the
// bounded 2-deep x prefetch in flight). 3 runtime barriers total. MB (7x16KB)
// staged over dead M16 slices, fill hidden under softmax/repack.
__global__ __launch_bounds__(1024, 4) void fused_mem_attn(
    const float* __restrict__ x, const unsigned short* __restrict__ M16,
    const unsigned short* __restrict__ MB, float* __restrict__ out) {
  __shared__ alignas(128) char lds[131072];

  const int tid = threadIdx.x;   // 0..1023
  const int wave = tid >> 6;     // 0..15
  const int lane = tid & 63;
  const int t16 = lane & 15;
  const int h = lane >> 4;

  // Score-table staging swizzle (proven pair): thread owns physical 16B-block
  // tid of each 16KB slice; fetches logical Lb = tid ^ ((tid>>3)&7).
  const int Lb = tid ^ ((tid >> 3) & 7);
  const int srcOff = (Lb >> 2) * 512 + (Lb & 3) * 16;  // byte in [256 rows][64B]
  // Reader-side swizzled 16B-block offset within a 1KB (16-row) tile.
  const int q16 = ((((t16 << 2) + h) ^ (t16 >> 1)) << 4);

  const long gtok0 = (long)blockIdx.x * 256;
  const int b = (int)(gtok0 >> 14);
  const int bn0 = (int)(gtok0 & 16383);
  const float* xb = x + ((long)b << 22) + bn0 + (wave * 16 + t16);
  // PV store base: token = wave*16 + 4h + r (r in the f32x4), channel = ct*16+t16
  float* outT = out + ((long)b << 22) + bn0 + (wave * 16 + 4 * h) + ((long)t16 << 14);

  const char* M16B = (const char*)M16;
  const char* MBB = (const char*)MB;

#define XLOAD(ks)                                                              \
  _Pragma("unroll") for (int j = 0; j < 8; ++j) {                              \
    xr[(ks) % 3][j] = xb[(long)((ks) * 32 + h * 8 + j) << 14];                 \
  }

  float xr[3][8];
  f32x4 acc[14] = {};  // acc[13] stays exactly 0 (padding slots 208..223)

#define COMPUTE(ks)                                                            \
  {                                                                            \
    if ((ks) < 6) XLOAD((ks) + 2);                                             \
    h16x8 xh;                                                                  \
    _Pragma("unroll") for (int j = 0; j < 8; ++j)                              \
        xh[j] = (_Float16)xr[(ks) % 3][j];                                     \
    const char* sb = lds + (ks) * 16384;                                       \
    __builtin_amdgcn_s_setprio(1);                                             \
    _Pragma("unroll") for (int tt = 0; tt < 13; ++tt) {                        \
      const h16x8 ah = *(const h16x8*)(sb + tt * 1024 + q16);                  \
      acc[tt] = MFMA16F(ah, xh, acc[tt]);                                      \
    }                                                                          \
    __builtin_amdgcn_s_setprio(0);                                             \
    FENCE();                                                                   \
  }

  // ---- prologue: 2-deep x prefetch + stage ALL 8 M16 slices; barrier #1 ----
  XLOAD(0);
  XLOAD(1);
#pragma unroll
  for (int ks = 0; ks < 8; ++ks)
    GLOAD16(M16B + srcOff + ks * 64, lds + ks * 16384 + tid * 16);
  __syncthreads();

  // ---- score phase: BARRIER-FREE, zero global fragment loads ----
  COMPUTE(0) COMPUTE(1) COMPUTE(2) COMPUTE(3)
  COMPUTE(4) COMPUTE(5) COMPUTE(6) COMPUTE(7)

  __syncthreads();  // barrier #2: all waves done reading M16 LDS

  // ---- stage ALL of MB (7 x 16KB, LINEAR dest/src: no swizzle needed) over
  //      the dead score slices; fill hides under softmax + repack ----
#pragma unroll
  for (int k = 0; k < 7; ++k)
    GLOAD16(MBB + k * 16384 + tid * 16, lds + k * 16384 + tid * 16);

  // ---- softmax over slots (token column = lane&15; slot row = 4h+r) ----
  float m = -3.0e38f;
#pragma unroll
  for (int tt = 0; tt < 12; ++tt)
#pragma unroll
    for (int r = 0; r < 4; ++r) m = fmaxf(m, acc[tt][r]);
#pragma unroll
  for (int r = 0; r < 4; ++r)
    if (192 + h * 4 + r < 200) m = fmaxf(m, acc[12][r]);
  m = fmaxf(m, __shfl_xor(m, 16, 64));
  m = fmaxf(m, __shfl_xor(m, 32, 64));
  float s = 0.f;
#pragma unroll
  for (int tt = 0; tt < 12; ++tt)
#pragma unroll
    for (int r = 0; r < 4; ++r) {
      const float p = __expf(acc[tt][r] - m);
      acc[tt][r] = p;
      s += p;
    }
#pragma unroll
  for (int r = 0; r < 4; ++r) {
    const bool ok = (192 + h * 4 + r) < 200;
    const float p = ok ? __expf(acc[12][r] - m) : 0.f;
    acc[12][r] = p;
    s += p;
  }
  s += __shfl_xor(s, 16, 64);
  s += __shfl_xor(s, 32, 64);
  const float inv = 1.f / s;

  // ---- repack P into PV A-fragments, inv folded in (pure register):
  //      pa[kk][j] = inv * acc[2kk + (j>>2)][j&3]  (same lane, same h) ----
  h16x8 pa[7];
#pragma unroll
  for (int kk = 0; kk < 7; ++kk)
#pragma unroll
    for (int j = 0; j < 8; ++j)
      pa[kk][j] = (_Float16)(inv * acc[2 * kk + (j >> 2)][j & 3]);

  __syncthreads();  // barrier #3: MB resident

  // ---- PV: D[tok][c] = P*M. B-fragments linear from LDS (conflict-free);
  //      output f32x4 = 4 consecutive tokens -> ONE 16B dwordx4 store ----
#pragma unroll
  for (int ct = 0; ct < 16; ++ct) {
    f32x4 a2 = {0.f, 0.f, 0.f, 0.f};
    __builtin_amdgcn_s_setprio(1);
#pragma unroll
    for (int kk = 0; kk < 7; ++kk) {
      const h16x8 bt = *(const h16x8*)(lds + kk * 16384 + ct * 1024 + lane * 16);
      a2 = MFMA16F(pa[kk], bt, a2);
    }
    __builtin_amdgcn_s_setprio(0);
    *(f32x4*)(outT + ((long)ct << 18)) = a2;
  }
#undef XLOAD
#undef COMPUTE
}

extern "C" void kernel_launch(void* const* d_in, const int* in_sizes, int n_in,
                              void* d_out, int out_size, void* d_ws, size_t ws_size,
                              hipStream_t stream) {
  const float* x = (const float*)d_in[0];
  const float* mem = (const float*)d_in[1];
  float* out = (float*)d_out;

  unsigned short* M16 = (unsigned short*)d_ws;   // [256][256] fp16 row-major
  unsigned short* MB = M16 + 256 * 256;          // [7][16][4][16][8] fp16 B-frag tiling

  prep_mem<<<dim3(256), dim3(256), 0, stream>>>(mem, M16, MB);
  fused_mem_attn<<<dim3(512), dim3(1024), 0, stream>>>(x, M16, MB, out);
}

// Round 20
// 61.319 us; speedup vs baseline: 2.3316x; 1.0131x over previous
//
#include <hip/hip_runtime.h>

typedef _Float16 h16x8 __attribute__((ext_vector_type(8)));
typedef float f32x4 __attribute__((ext_vector_type(4)));

#define MFMA16F(a, b, c) __builtin_amdgcn_mfma_f32_16x16x32_f16((a), (b), (c), 0, 0, 0)

#define GLOAD16(gp, lp)                                                        \
  __builtin_amdgcn_global_load_lds(                                            \
      (const __attribute__((address_space(1))) unsigned int*)(gp),             \
      (__attribute__((address_space(3))) unsigned int*)(lp), 16, 0, 0)

// Selective fence: pins VMEM ops (blocks 0x10|0x20|0x40 from crossing -- the
// R10 spill antidote) while ALLOWING ALU/VALU/SALU/MFMA/DS ops to cross
// (0x1|0x2|0x4|0x8|0x80|0x100|0x200 = 0x38F) so the scheduler can issue the
// next slice's ds_reads under this slice's MFMAs (LDS||MFMA overlap).
#define VFENCE() __builtin_amdgcn_sched_barrier(0x38F)

// Geometry: x (8, 256, 16384) fp32; mem (200, 256) fp32; out (8, 256, 16384) fp32.
// Slots padded 200 -> 256 with zero rows.
//
// Score: SINGLE-PASS fp16 (m16 * fp16(x), fp32 accum) -- R19-proven, absmax
// 0.03125 (PV-rounding dominated; xl-pass was unnecessary).
// PV: R13 orientation (P = A-operand, pure-register from score acc; MB =
// B-frag-tiled mem table, linear LDS reads; token-contiguous f32x4 stores).
// CRITICAL: acc MUST be [14] -- repack reads acc[13] for kk=6,j>=4 (zero pad).

// ---------------- prep: mem -> fp16 M16 (row-major) + MB (B-frag-tiled) ----------------
__global__ __launch_bounds__(256) void prep_mem(const float* __restrict__ mem,
                                                unsigned short* __restrict__ M16,
                                                unsigned short* __restrict__ MB) {
  const int s = blockIdx.x;   // slot (padded 0..255)
  const int c = threadIdx.x;  // channel
  const float v = (s < 200) ? mem[s * 256 + c] : 0.0f;
  const _Float16 hv = (_Float16)v;
  const unsigned short hb = __builtin_bit_cast(unsigned short, hv);
  M16[s * 256 + c] = hb;
  if (s < 224) {
    // invert s(kk,h,j): s = 32kk + 16*(j>>2) + 4h + (j&3)
    const int kk = s >> 5;
    const int th = (s >> 4) & 1;   // j>>2
    const int hh = (s >> 2) & 3;
    const int rr = s & 3;          // j&3
    const int j = th * 4 + rr;
    MB[kk * 8192 + (c >> 4) * 512 + hh * 128 + (c & 15) * 8 + j] = hb;
  }
}

// ---------------- fused kernel ----------------
// Block = 16 waves x 16 tokens = 256 tokens, 1024 threads. Grid = 512.
// LDS 128KB = ALL 8 M16 slices resident; score phase BARRIER-FREE (only the
// bounded 2-deep x prefetch in flight). 3 runtime barriers total. MB (7x16KB)
// staged over dead M16 slices, fill hidden under softmax/repack.
__global__ __launch_bounds__(1024, 4) void fused_mem_attn(
    const float* __restrict__ x, const unsigned short* __restrict__ M16,
    const unsigned short* __restrict__ MB, float* __restrict__ out) {
  __shared__ alignas(128) char lds[131072];

  const int tid = threadIdx.x;   // 0..1023
  const int wave = tid >> 6;     // 0..15
  const int lane = tid & 63;
  const int t16 = lane & 15;
  const int h = lane >> 4;

  // Score-table staging swizzle (proven pair): thread owns physical 16B-block
  // tid of each 16KB slice; fetches logical Lb = tid ^ ((tid>>3)&7).
  const int Lb = tid ^ ((tid >> 3) & 7);
  const int srcOff = (Lb >> 2) * 512 + (Lb & 3) * 16;  // byte in [256 rows][64B]
  // Reader-side swizzled 16B-block offset within a 1KB (16-row) tile.
  const int q16 = ((((t16 << 2) + h) ^ (t16 >> 1)) << 4);

  const long gtok0 = (long)blockIdx.x * 256;
  const int b = (int)(gtok0 >> 14);
  const int bn0 = (int)(gtok0 & 16383);
  const float* xb = x + ((long)b << 22) + bn0 + (wave * 16 + t16);
  // PV store base: token = wave*16 + 4h + r (r in the f32x4), channel = ct*16+t16
  float* outT = out + ((long)b << 22) + bn0 + (wave * 16 + 4 * h) + ((long)t16 << 14);

  const char* M16B = (const char*)M16;
  const char* MBB = (const char*)MB;

#define XLOAD(ks)                                                              \
  _Pragma("unroll") for (int j = 0; j < 8; ++j) {                              \
    xr[(ks) % 3][j] = xb[(long)((ks) * 32 + h * 8 + j) << 14];                 \
  }

  float xr[3][8];
  f32x4 acc[14] = {};  // acc[13] stays exactly 0 (padding slots 208..223)

#define COMPUTE(ks)                                                            \
  {                                                                            \
    if ((ks) < 6) XLOAD((ks) + 2);                                             \
    h16x8 xh;                                                                  \
    _Pragma("unroll") for (int j = 0; j < 8; ++j)                              \
        xh[j] = (_Float16)xr[(ks) % 3][j];                                     \
    const char* sb = lds + (ks) * 16384;                                       \
    __builtin_amdgcn_s_setprio(1);                                             \
    _Pragma("unroll") for (int tt = 0; tt < 13; ++tt) {                        \
      const h16x8 ah = *(const h16x8*)(sb + tt * 1024 + q16);                  \
      acc[tt] = MFMA16F(ah, xh, acc[tt]);                                      \
    }                                                                          \
    __builtin_amdgcn_s_setprio(0);                                             \
    VFENCE();                                                                  \
  }

  // ---- prologue: 2-deep x prefetch + stage ALL 8 M16 slices; barrier #1 ----
  XLOAD(0);
  XLOAD(1);
#pragma unroll
  for (int ks = 0; ks < 8; ++ks)
    GLOAD16(M16B + srcOff + ks * 64, lds + ks * 16384 + tid * 16);
  __syncthreads();

  // ---- score phase: BARRIER-FREE, zero global fragment loads;
  //      VFENCE lets ds_reads of slice k+1 issue under slice k's MFMAs ----
  COMPUTE(0) COMPUTE(1) COMPUTE(2) COMPUTE(3)
  COMPUTE(4) COMPUTE(5) COMPUTE(6) COMPUTE(7)

  __syncthreads();  // barrier #2: all waves done reading M16 LDS

  // ---- stage ALL of MB (7 x 16KB, LINEAR dest/src: no swizzle needed) over
  //      the dead score slices; fill hides under softmax + repack ----
#pragma unroll
  for (int k = 0; k < 7; ++k)
    GLOAD16(MBB + k * 16384 + tid * 16, lds + k * 16384 + tid * 16);

  // ---- softmax over slots (token column = lane&15; slot row = 4h+r) ----
  float m = -3.0e38f;
#pragma unroll
  for (int tt = 0; tt < 12; ++tt)
#pragma unroll
    for (int r = 0; r < 4; ++r) m = fmaxf(m, acc[tt][r]);
#pragma unroll
  for (int r = 0; r < 4; ++r)
    if (192 + h * 4 + r < 200) m = fmaxf(m, acc[12][r]);
  m = fmaxf(m, __shfl_xor(m, 16, 64));
  m = fmaxf(m, __shfl_xor(m, 32, 64));
  float s = 0.f;
#pragma unroll
  for (int tt = 0; tt < 12; ++tt)
#pragma unroll
    for (int r = 0; r < 4; ++r) {
      const float p = __expf(acc[tt][r] - m);
      acc[tt][r] = p;
      s += p;
    }
#pragma unroll
  for (int r = 0; r < 4; ++r) {
    const bool ok = (192 + h * 4 + r) < 200;
    const float p = ok ? __expf(acc[12][r] - m) : 0.f;
    acc[12][r] = p;
    s += p;
  }
  s += __shfl_xor(s, 16, 64);
  s += __shfl_xor(s, 32, 64);
  const float inv = 1.f / s;

  // ---- repack P into PV A-fragments, inv folded in (pure register):
  //      pa[kk][j] = inv * acc[2kk + (j>>2)][j&3]  (same lane, same h) ----
  h16x8 pa[7];
#pragma unroll
  for (int kk = 0; kk < 7; ++kk)
#pragma unroll
    for (int j = 0; j < 8; ++j)
      pa[kk][j] = (_Float16)(inv * acc[2 * kk + (j >> 2)][j & 3]);

  __syncthreads();  // barrier #3: MB resident

  // ---- PV: D[tok][c] = P*M. B-fragments linear from LDS (conflict-free);
  //      output f32x4 = 4 consecutive tokens -> ONE 16B dwordx4 store ----
#pragma unroll
  for (int ct = 0; ct < 16; ++ct) {
    f32x4 a2 = {0.f, 0.f, 0.f, 0.f};
    __builtin_amdgcn_s_setprio(1);
#pragma unroll
    for (int kk = 0; kk < 7; ++kk) {
      const h16x8 bt = *(const h16x8*)(lds + kk * 16384 + ct * 1024 + lane * 16);
      a2 = MFMA16F(pa[kk], bt, a2);
    }
    __builtin_amdgcn_s_setprio(0);
    *(f32x4*)(outT + ((long)ct << 18)) = a2;
  }
#undef XLOAD
#undef COMPUTE
}

extern "C" void kernel_launch(void* const* d_in, const int* in_sizes, int n_in,
                              void* d_out, int out_size, void* d_ws, size_t ws_size,
                              hipStream_t stream) {
  const float* x = (const float*)d_in[0];
  const float* mem = (const float*)d_in[1];
  float* out = (float*)d_out;

  unsigned short* M16 = (unsigned short*)d_ws;   // [256][256] fp16 row-major
  unsigned short* MB = M16 + 256 * 256;          // [7][16][4][16][8] fp16 B-frag tiling

  prep_mem<<<dim3(256), dim3(256), 0, stream>>>(mem, M16, MB);
  fused_mem_attn<<<dim3(512), dim3(1024), 0, stream>>>(x, M16, MB, out);
}